// Round 4
// baseline (989.222 us; speedup 1.0000x reference)
//
#include <hip/hip_runtime.h>
#include <hip/hip_bf16.h>

// GraphConv: out = verts@W0^T + b0 + scatter_sum_undirected(verts@W1^T + b1)
// V=100000, E=1000000, D=64. fp32 in/out; edges int64 (or int32) detected.
//
// R13 -> R14: gather3/gather5 triangulation: 500K vs 2M wave-loads, 2x VALU
// delta, SAME ~50us => gather cost tracks DISTINCT 128B SEGMENTS (2M random
// row-fetches ~= per-CU line-fill throughput floor). Stop polishing gather
// instruction shape. Instead: (1) hist/scatter were 256x256 = 1 block/CU =
// 4 waves/CU -- latency-starved edge scans; now 256x1024 (16 waves/CU).
// (2) reorder+gather fused into gather7: per-bucket LDS fp32 accumulate
// (acc[128][65], 65-stride => 2-way bank alias = free) fed straight from
// bucket-grouped `entries` (counting sort + adj round-trip deleted); rows
// read as dwordx4 with 8 lanes/row (8 rows/inst); cnt via LDS hist pass.
//   hist(+prep): 256x1024; per-block LDS histogram over 782 buckets.
//   scan1/scan2: two-level exclusive scan of (bucket,block) counts.
//   scatter:     256x1024; pre-reserved runs; LDS atomics only. n|t<<17.
//   gather7:     per-bucket ds_add_f32 accumulate -> sbf bf16 + cnt.
//   matvec:      MFMA [X|S] @ [W0;W1]^T (unchanged).

#define NV 100000
#define NE 1000000
#define DIM 64
#define BSH 7                              // 128 vertices per bucket
#define NBUCK ((NV + 127) >> BSH)          // 782
#define NBLK 256                           // hist/scatter blocks
#define NTHR 1024                          // hist/scatter threads per block
#define EPB ((NE + NBLK - 1) / NBLK)       // 3907 edges per block
#define NTILE (NV / 16)                    // 6250 MFMA row-tiles exactly
#define ACCP 65                            // LDS acc row stride (floats)

typedef __attribute__((ext_vector_type(8))) short short8;   // 8 bf16
typedef __attribute__((ext_vector_type(4))) float f32x4;

// Per-wave edge-layout detection. int64 words: [a_lo,a_hi,...], hi==0 always
// (idx < 100000). int32 words: odd words random in [0,V). First 64 odd words
// all zero => int64 (FP prob ~ V^-64 ~ 0). Reads are L2-hot after first wave.
__device__ __forceinline__ bool detect_is64(const int* __restrict__ edges) {
    int v = edges[2 * (threadIdx.x & 63) + 1];
    return __ballot(v != 0) == 0ull;
}

__device__ __forceinline__ unsigned f2bf1(float f) {  // RNE fp32 -> bf16 bits
    unsigned u = __float_as_uint(f);
    return (u + 0x7fffu + ((u >> 16) & 1u)) >> 16;
}

__device__ __forceinline__ float bflo(unsigned u) {
    return __uint_as_float(u << 16);
}
__device__ __forceinline__ float bfhi(unsigned u) {
    return __uint_as_float(u & 0xffff0000u);
}

__device__ __forceinline__ short8 pack_bf8(float4 a, float4 b) {
    short8 r;
    r[0] = (short)f2bf1(a.x); r[1] = (short)f2bf1(a.y);
    r[2] = (short)f2bf1(a.z); r[3] = (short)f2bf1(a.w);
    r[4] = (short)f2bf1(b.x); r[5] = (short)f2bf1(b.y);
    r[6] = (short)f2bf1(b.z); r[7] = (short)f2bf1(b.w);
    return r;
}

// ---------------------------------------------------------------------------
// Pass 1: per-block bucket histogram (LDS atomics only; plain stores to
// cntmat[bucket][block]) + fused prep (verts fp32 -> vbf bf16 rows, 128 B).
// 1024 threads/block: 16 waves/CU so the streaming loads have MLP.
// ---------------------------------------------------------------------------
__global__ __launch_bounds__(NTHR)
void hist_kernel(const int* __restrict__ edges, int* __restrict__ cntmat,
                 const float* __restrict__ verts, uint2* __restrict__ vbf) {
    __shared__ int hist[NBUCK];
    for (int k = threadIdx.x; k < NBUCK; k += NTHR) hist[k] = 0;
    const bool is64 = detect_is64(edges);
    __syncthreads();
    const int eb = blockIdx.x * EPB;
    const int ee = min(NE, eb + EPB);
    for (int e = eb + threadIdx.x; e < ee; e += NTHR) {
        int a, b;
        if (is64) { int4 q = ((const int4*)edges)[e]; a = q.x; b = q.z; }
        else      { int2 q = ((const int2*)edges)[e]; a = q.x; b = q.y; }
        atomicAdd(&hist[a >> BSH], 1);
        atomicAdd(&hist[b >> BSH], 1);
    }
    __syncthreads();
    for (int k = threadIdx.x; k < NBUCK; k += NTHR)
        cntmat[k * NBLK + blockIdx.x] = hist[k];

    // Fused prep: one float4 per iter -> uint2 (4 bf16). Independent of hist.
    const long np = (long)NV * (DIM / 4);
    for (long i = (long)blockIdx.x * NTHR + threadIdx.x; i < np; i += (long)NTHR * NBLK) {
        float4 v = ((const float4*)verts)[i];
        uint2 w;
        w.x = f2bf1(v.x) | (f2bf1(v.y) << 16);
        w.y = f2bf1(v.z) | (f2bf1(v.w) << 16);
        vbf[i] = w;
    }
}

// Exclusive scan of the 256 per-block counts within one bucket; total -> btot.
__global__ __launch_bounds__(256)
void scan1_kernel(int* __restrict__ cntmat, int* __restrict__ btot) {
    __shared__ int s[256];
    const int k = blockIdx.x, t = threadIdx.x;
    const int c = cntmat[k * NBLK + t];
    s[t] = c;
    __syncthreads();
    for (int off = 1; off < 256; off <<= 1) {
        int v = (t >= off) ? s[t - off] : 0;
        __syncthreads();
        s[t] += v;
        __syncthreads();
    }
    cntmat[k * NBLK + t] = s[t] - c;        // exclusive prefix within bucket
    if (t == 255) btot[k] = s[255];
}

// Exclusive scan of bucket totals (single block, Hillis-Steele over 1024 pad).
__global__ __launch_bounds__(256)
void scan2_kernel(const int* __restrict__ btot, int* __restrict__ bbase) {
    __shared__ int s[1024];
    const int t = threadIdx.x;
    for (int r = 0; r < 4; ++r) {
        int i = t + 256 * r;
        s[i] = (i < NBUCK) ? btot[i] : 0;
    }
    __syncthreads();
    for (int off = 1; off < 1024; off <<= 1) {
        int v[4];
        for (int r = 0; r < 4; ++r) {
            int i = t + 256 * r;
            v[r] = (i >= off) ? s[i - off] : 0;
        }
        __syncthreads();
        for (int r = 0; r < 4; ++r) s[t + 256 * r] += v[r];
        __syncthreads();
    }
    for (int r = 0; r < 4; ++r) {
        int i = t + 256 * r;
        if (i < NBUCK) bbase[i] = s[i] - btot[i];
    }
}

// ---------------------------------------------------------------------------
// Pass 2: deterministic scatter. Each block's run inside each bucket was
// pre-reserved by scan1/scan2, so slot assignment needs only LDS atomics.
// Entry packing: n (17 bits) | t_local (7 bits) << 17. 1024 threads/block.
// ---------------------------------------------------------------------------
__global__ __launch_bounds__(NTHR)
void scatter_kernel(const int* __restrict__ edges, const int* __restrict__ cntmat,
                    const int* __restrict__ bbase, unsigned* __restrict__ entries) {
    __shared__ int cur[NBUCK];
    const bool is64 = detect_is64(edges);
    for (int k = threadIdx.x; k < NBUCK; k += NTHR)
        cur[k] = bbase[k] + cntmat[k * NBLK + blockIdx.x];
    __syncthreads();
    const int eb = blockIdx.x * EPB;
    const int ee = min(NE, eb + EPB);
    for (int e = eb + threadIdx.x; e < ee; e += NTHR) {
        int a, b;
        if (is64) { int4 q = ((const int4*)edges)[e]; a = q.x; b = q.z; }
        else      { int2 q = ((const int2*)edges)[e]; a = q.x; b = q.y; }
        const int pa = atomicAdd(&cur[a >> BSH], 1);
        entries[pa] = (unsigned)b | ((unsigned)(a & 127) << 17);
        const int pb = atomicAdd(&cur[b >> BSH], 1);
        entries[pb] = (unsigned)a | ((unsigned)(b & 127) << 17);
    }
}

// ---------------------------------------------------------------------------
// Fused reorder+gather: one block (512 thr, 8 waves) per bucket. Bucket's
// entries are consumed directly (no counting sort, no adj array): each
// 8-lane group reads one neighbor row as dwordx4 (8 rows per instruction)
// and ds_add_f32's 8 features into acc[t_local][*]. Bank math: addr =
// t*65 + sub*8 + r, 65 = 1 mod 32 => (t + 8*sub + r) % 32 -> ~2-way = free.
// cnt from a dedicated LDS hist pass (also warms L2 with the entries run).
// ---------------------------------------------------------------------------
__global__ __launch_bounds__(512)
void gather7_kernel(const uint2* __restrict__ vbf, const unsigned* __restrict__ entries,
                    const int* __restrict__ bbase, const int* __restrict__ btot,
                    unsigned* __restrict__ sbf, int* __restrict__ cnt) {
    __shared__ float acc[128 * ACCP];
    __shared__ int dcnt[128];
    const int tid = threadIdx.x;
    for (int i = tid; i < 128 * ACCP; i += 512) acc[i] = 0.f;
    if (tid < 128) dcnt[tid] = 0;
    __syncthreads();

    const int k = blockIdx.x;
    const int nE = btot[k];
    const int eb = bbase[k];

    // Degree hist (exact cnt for matvec bias) + entry warm-up.
    for (int i = tid; i < nE; i += 512)
        atomicAdd(&dcnt[entries[eb + i] >> 17], 1);

    const int lane = tid & 63;
    const int wv = tid >> 6;            // 8 waves
    const int grp = lane >> 3;          // neighbor slot 0..7
    const int sub = lane & 7;           // 16B chunk within the 128B row
    const uint4* __restrict__ vrow = (const uint4*)vbf;   // 8 uint4 per row
    const int last = nE - 1;

    for (int c = wv * 16; c < nE; c += 8 * 16) {
        const int i0 = c + grp;
        const int i1 = c + 8 + grp;
        const bool ok0 = i0 < nE, ok1 = i1 < nE;
        const unsigned e0 = entries[eb + (ok0 ? i0 : last)];
        const unsigned e1 = entries[eb + (ok1 ? i1 : last)];
        const uint4 w0 = vrow[(size_t)(e0 & 0x1FFFFu) * 8 + sub];
        const uint4 w1 = vrow[(size_t)(e1 & 0x1FFFFu) * 8 + sub];
        if (ok0) {
            float* a = &acc[(e0 >> 17) * ACCP + sub * 8];
            atomicAdd(a + 0, bflo(w0.x)); atomicAdd(a + 1, bfhi(w0.x));
            atomicAdd(a + 2, bflo(w0.y)); atomicAdd(a + 3, bfhi(w0.y));
            atomicAdd(a + 4, bflo(w0.z)); atomicAdd(a + 5, bfhi(w0.z));
            atomicAdd(a + 6, bflo(w0.w)); atomicAdd(a + 7, bfhi(w0.w));
        }
        if (ok1) {
            float* a = &acc[(e1 >> 17) * ACCP + sub * 8];
            atomicAdd(a + 0, bflo(w1.x)); atomicAdd(a + 1, bfhi(w1.x));
            atomicAdd(a + 2, bflo(w1.y)); atomicAdd(a + 3, bfhi(w1.y));
            atomicAdd(a + 4, bflo(w1.z)); atomicAdd(a + 5, bfhi(w1.z));
            atomicAdd(a + 6, bflo(w1.w)); atomicAdd(a + 7, bfhi(w1.w));
        }
    }
    __syncthreads();

    // Pack LDS fp32 -> bf16 sbf rows (coalesced dwordx4) + cnt.
    const int vb0 = k << BSH;
    const int nv = min(128, NV - vb0);
    for (int u = tid; u < nv * 8; u += 512) {
        const int row = u >> 3, s8 = u & 7;
        const float* a = &acc[row * ACCP + s8 * 8];
        uint4 o;
        o.x = f2bf1(a[0]) | (f2bf1(a[1]) << 16);
        o.y = f2bf1(a[2]) | (f2bf1(a[3]) << 16);
        o.z = f2bf1(a[4]) | (f2bf1(a[5]) << 16);
        o.w = f2bf1(a[6]) | (f2bf1(a[7]) << 16);
        ((uint4*)sbf)[(size_t)(vb0 + row) * 8 + s8] = o;
    }
    if (tid < nv) cnt[vb0 + tid] = dcnt[tid];
}

// ---------------------------------------------------------------------------
// MFMA matvec: out[V,64] = A(V x 128) @ Bw(128 x 64) + b0 + deg*b1, where
// A = [x_bf16 | s_bf16], Bw = [W0^T; W1^T]. mfma_f32_16x16x32_bf16:
//   A-frag:  lane holds A[m = lane&15][k = quad*8 + j]
//   B-frag:  lane holds B[k = quad*8 + j][n = lane&15]  (mirror of A)
//   C/D:     lane holds D[row = quad*4 + reg][col = lane&15]
// One wave per 16-vertex tile; 16 B-frags hoisted (weights, L2-hot).
// A chunks 0,1 read vbf; chunks 2,3 read sbf (both bf16 rows, 128 B).
// ---------------------------------------------------------------------------
__global__ __launch_bounds__(256)
void matvec_mfma_kernel(const uint2* __restrict__ vbf,
                        const unsigned* __restrict__ sbf,
                        const float* __restrict__ w0,
                        const float* __restrict__ b0,
                        const float* __restrict__ w1,
                        const float* __restrict__ b1,
                        const int* __restrict__ cnt,
                        float* __restrict__ out) {
    const int lane = threadIdx.x & 63;
    const int quad = lane >> 4;
    const int n = lane & 15;
    const int wave = (int)((blockIdx.x * blockDim.x + threadIdx.x) >> 6);
    const int nwaves = (int)((gridDim.x * blockDim.x) >> 6);

    // Hoist 16 B-fragments: B[c][t], c = K-chunk (0,1: W0; 2,3: W1), t = col-tile.
    // B[k_g][n_g] = W[d = t*16+n][k = (c&1)*32 + quad*8 + j]  (y_d = sum_k W[d][k] A[k])
    short8 B[4][4];
#pragma unroll
    for (int c = 0; c < 4; ++c) {
        const float* wsrc = (c < 2) ? w0 : w1;
        const int kb = (c & 1) * 32 + quad * 8;
#pragma unroll
        for (int t = 0; t < 4; ++t) {
            const int d = t * 16 + n;
            const float4 p = *(const float4*)(wsrc + d * DIM + kb);
            const float4 q = *(const float4*)(wsrc + d * DIM + kb + 4);
            B[c][t] = pack_bf8(p, q);
        }
    }
    float bias0[4], bias1[4];
#pragma unroll
    for (int t = 0; t < 4; ++t) { bias0[t] = b0[t * 16 + n]; bias1[t] = b1[t * 16 + n]; }

    const short8* vb8 = (const short8*)vbf;    // 8 uint16 = 16 B per frag
    const short8* sb8 = (const short8*)sbf;

    for (int tile = wave; tile < NTILE; tile += nwaves) {
        const int base = tile * 16;
        const long v = base + n;               // this lane's A row
        f32x4 acc[4] = {{0.f,0.f,0.f,0.f},{0.f,0.f,0.f,0.f},
                        {0.f,0.f,0.f,0.f},{0.f,0.f,0.f,0.f}};

        // K-chunks 0,1: x rows from vbf
#pragma unroll
        for (int c = 0; c < 2; ++c) {
            const short8 A = vb8[v * 8 + c * 4 + quad];
#pragma unroll
            for (int t = 0; t < 4; ++t)
                acc[t] = __builtin_amdgcn_mfma_f32_16x16x32_bf16(A, B[c][t], acc[t], 0, 0, 0);
        }
        // K-chunks 2,3: s rows from sbf (already bf16)
#pragma unroll
        for (int c = 2; c < 4; ++c) {
            const short8 A = sb8[v * 8 + (c - 2) * 4 + quad];
#pragma unroll
            for (int t = 0; t < 4; ++t)
                acc[t] = __builtin_amdgcn_mfma_f32_16x16x32_bf16(A, B[c][t], acc[t], 0, 0, 0);
        }
        // Epilogue: D[row=quad*4+reg][col=n] + b0[d] + deg*b1[d]
#pragma unroll
        for (int r = 0; r < 4; ++r) {
            const int row = base + quad * 4 + r;
            const float dg = (float)cnt[row];
#pragma unroll
            for (int t = 0; t < 4; ++t)
                out[(long)row * DIM + t * 16 + n] = acc[t][r] + fmaf(dg, bias1[t], bias0[t]);
        }
    }
}

// ==========================================================================

extern "C" void kernel_launch(void* const* d_in, const int* in_sizes, int n_in,
                              void* d_out, int out_size, void* d_ws, size_t ws_size,
                              hipStream_t stream) {
    const float* verts = (const float*)d_in[0];
    const int*   edges = (const int*)d_in[1];
    const float* w0_w  = (const float*)d_in[2];
    const float* w0_b  = (const float*)d_in[3];
    const float* w1_w  = (const float*)d_in[4];
    const float* w1_b  = (const float*)d_in[5];
    float* out = (float*)d_out;

    // Workspace: vbf | sbf | entries | cntmat | cnt | bbase | btot.
    // Everything fully written -> no memset.
    char* p = (char*)d_ws;
    uint2*    vbf     = (uint2*)p;    p += (size_t)NV * DIM * 2;
    unsigned* sbf     = (unsigned*)p; p += (size_t)NV * DIM * 2;
    unsigned* entries = (unsigned*)p; p += (size_t)2 * NE * 4;
    int*      cntmat  = (int*)p;      p += (size_t)NBUCK * NBLK * 4;
    int*      cnt     = (int*)p;      p += (size_t)NV * 4;
    int*      bbase   = (int*)p;      p += ((size_t)NBUCK * 4 + 15) & ~(size_t)15;
    int*      btot    = (int*)p;      p += ((size_t)NBUCK * 4 + 15) & ~(size_t)15;

    hist_kernel<<<NBLK, NTHR, 0, stream>>>(edges, cntmat, verts, vbf);
    scan1_kernel<<<NBUCK, 256, 0, stream>>>(cntmat, btot);
    scan2_kernel<<<1, 256, 0, stream>>>(btot, bbase);
    scatter_kernel<<<NBLK, NTHR, 0, stream>>>(edges, cntmat, bbase, entries);
    gather7_kernel<<<NBUCK, 512, 0, stream>>>(vbf, entries, bbase, btot, sbf, cnt);
    // 6250 tiles, one per wave: 1563 blocks x 4 waves (grid-stride guard)
    matvec_mfma_kernel<<<1563, 256, 0, stream>>>(vbf, sbf, w0_w, w0_b,
                                                 w1_w, w1_b, cnt, out);
}

// Round 5
// 220.256 us; speedup vs baseline: 4.4912x; 4.4912x over previous
//
#include <hip/hip_runtime.h>
#include <hip/hip_bf16.h>

// GraphConv: out = verts@W0^T + b0 + scatter_sum_undirected(verts@W1^T + b1)
// V=100000, E=1000000, D=64. fp32 in/out; edges int64 (or int32) detected.
//
// R14 -> R15: gather7 (bucket-block LDS accumulate) hit the same latency wall
// as gather2 (849us, VALU 1.1%) -- per-bucket blocks are structurally serial.
// RULE: gather stays wave-per-vertex register-accumulate (proven 47.5us).
// Remaining fat was scatter's write amplification (2M 4B stores into ~40B
// runs spread over 8MB => ~128MB line traffic). Fix: two-level routing.
//   hist(+prep): 256x1024; LDS hist over 782 buckets, folded to 49 bins
//                (2048 verts) at write-out -> cbnt[bin][block].
//   scanb:       49 blocks: exclusive scan of cbnt across blocks -> bintot.
//   scanc:       1 block: exclusive scan of bintot -> binbase.
//   route:       256x1024; entries into per-(block,bin) pre-reserved runs
//                (avg 640B sequential bursts => write amp ~1x). Entry =
//                n (17b) | vlocal (11b) << 17.
//   sort2:       one block per bin: counting-sort 41K entries to per-vertex
//                CSR adj + vstart + cnt; scattered writes confined to the
//                bin's ~163KB window (L2-resident).
//   gather8:     R12's gather3 (wave/vertex, uint2 rows, shfl broadcast),
//                output packed bf16 sbf.
//   matvec:      MFMA [X|S] @ [W0;W1]^T (unchanged).

#define NV 100000
#define NE 1000000
#define DIM 64
#define BSH 7                              // 128 vertices per bucket (hist)
#define NBUCK ((NV + 127) >> BSH)          // 782
#define BINSH 11                           // 2048 vertices per bin
#define NBIN ((NV + 2047) >> BINSH)        // 49
#define NBLK 256                           // hist/route blocks
#define NTHR 1024                          // hist/route threads per block
#define EPB ((NE + NBLK - 1) / NBLK)       // 3907 edges per block
#define NTILE (NV / 16)                    // 6250 MFMA row-tiles exactly

typedef __attribute__((ext_vector_type(8))) short short8;   // 8 bf16
typedef __attribute__((ext_vector_type(4))) float f32x4;

// Per-wave edge-layout detection. int64 words: [a_lo,a_hi,...], hi==0 always
// (idx < 100000). int32 words: odd words random in [0,V). First 64 odd words
// all zero => int64 (FP prob ~ V^-64 ~ 0). Reads are L2-hot after first wave.
__device__ __forceinline__ bool detect_is64(const int* __restrict__ edges) {
    int v = edges[2 * (threadIdx.x & 63) + 1];
    return __ballot(v != 0) == 0ull;
}

__device__ __forceinline__ unsigned f2bf1(float f) {  // RNE fp32 -> bf16 bits
    unsigned u = __float_as_uint(f);
    return (u + 0x7fffu + ((u >> 16) & 1u)) >> 16;
}

__device__ __forceinline__ short8 pack_bf8(float4 a, float4 b) {
    short8 r;
    r[0] = (short)f2bf1(a.x); r[1] = (short)f2bf1(a.y);
    r[2] = (short)f2bf1(a.z); r[3] = (short)f2bf1(a.w);
    r[4] = (short)f2bf1(b.x); r[5] = (short)f2bf1(b.y);
    r[6] = (short)f2bf1(b.z); r[7] = (short)f2bf1(b.w);
    return r;
}

// ---------------------------------------------------------------------------
// Pass 1: per-block bucket histogram (contention spread over 782 LDS slots),
// folded to 49 bins at write-out. Fused prep: verts fp32 -> vbf bf16 rows.
// ---------------------------------------------------------------------------
__global__ __launch_bounds__(NTHR)
void hist_kernel(const int* __restrict__ edges, int* __restrict__ cbnt,
                 const float* __restrict__ verts, uint2* __restrict__ vbf) {
    __shared__ int hist[NBUCK];
    for (int k = threadIdx.x; k < NBUCK; k += NTHR) hist[k] = 0;
    const bool is64 = detect_is64(edges);
    __syncthreads();
    const int eb = blockIdx.x * EPB;
    const int ee = min(NE, eb + EPB);
    for (int e = eb + threadIdx.x; e < ee; e += NTHR) {
        int a, b;
        if (is64) { int4 q = ((const int4*)edges)[e]; a = q.x; b = q.z; }
        else      { int2 q = ((const int2*)edges)[e]; a = q.x; b = q.y; }
        atomicAdd(&hist[a >> BSH], 1);
        atomicAdd(&hist[b >> BSH], 1);
    }
    __syncthreads();
    // Fold 16 buckets -> 1 bin (bin = vertex >> 11 = bucket >> 4).
    if (threadIdx.x < NBIN) {
        int s = 0;
        const int k0 = threadIdx.x << 4;
#pragma unroll
        for (int j = 0; j < 16; ++j) {
            const int k = k0 + j;
            if (k < NBUCK) s += hist[k];
        }
        cbnt[threadIdx.x * NBLK + blockIdx.x] = s;
    }

    // Fused prep: one float4 per iter -> uint2 (4 bf16). Independent of hist.
    const long np = (long)NV * (DIM / 4);
    for (long i = (long)blockIdx.x * NTHR + threadIdx.x; i < np; i += (long)NTHR * NBLK) {
        float4 v = ((const float4*)verts)[i];
        uint2 w;
        w.x = f2bf1(v.x) | (f2bf1(v.y) << 16);
        w.y = f2bf1(v.z) | (f2bf1(v.w) << 16);
        vbf[i] = w;
    }
}

// Exclusive scan of the 256 per-block counts within one bin; total -> bintot.
__global__ __launch_bounds__(256)
void scanb_kernel(int* __restrict__ cbnt, int* __restrict__ bintot) {
    __shared__ int s[256];
    const int k = blockIdx.x, t = threadIdx.x;
    const int c = cbnt[k * NBLK + t];
    s[t] = c;
    __syncthreads();
    for (int off = 1; off < 256; off <<= 1) {
        int v = (t >= off) ? s[t - off] : 0;
        __syncthreads();
        s[t] += v;
        __syncthreads();
    }
    cbnt[k * NBLK + t] = s[t] - c;          // exclusive prefix within bin
    if (t == 255) bintot[k] = s[255];
}

// Exclusive scan of the 49 bin totals (single tiny block).
__global__ __launch_bounds__(64)
void scanc_kernel(const int* __restrict__ bintot, int* __restrict__ binbase) {
    __shared__ int s[64];
    const int t = threadIdx.x;
    const int c = (t < NBIN) ? bintot[t] : 0;
    s[t] = c;
    __syncthreads();
    for (int off = 1; off < 64; off <<= 1) {
        int v = (t >= off) ? s[t - off] : 0;
        __syncthreads();
        s[t] += v;
        __syncthreads();
    }
    if (t < NBIN) binbase[t] = s[t] - c;
}

// ---------------------------------------------------------------------------
// Pass 2: route entries into per-(block,bin) pre-reserved runs (avg 640 B =>
// sequential write bursts). Entry: n (17b) | vlocal (11b) << 17.
// ---------------------------------------------------------------------------
__global__ __launch_bounds__(NTHR)
void route_kernel(const int* __restrict__ edges, const int* __restrict__ cbnt,
                  const int* __restrict__ binbase, unsigned* __restrict__ rbuf) {
    __shared__ int cur[NBIN];
    const bool is64 = detect_is64(edges);
    if (threadIdx.x < NBIN)
        cur[threadIdx.x] = binbase[threadIdx.x] + cbnt[threadIdx.x * NBLK + blockIdx.x];
    __syncthreads();
    const int eb = blockIdx.x * EPB;
    const int ee = min(NE, eb + EPB);
    for (int e = eb + threadIdx.x; e < ee; e += NTHR) {
        int a, b;
        if (is64) { int4 q = ((const int4*)edges)[e]; a = q.x; b = q.z; }
        else      { int2 q = ((const int2*)edges)[e]; a = q.x; b = q.y; }
        const int pa = atomicAdd(&cur[a >> BINSH], 1);
        rbuf[pa] = (unsigned)b | ((unsigned)(a & 2047) << 17);
        const int pb = atomicAdd(&cur[b >> BINSH], 1);
        rbuf[pb] = (unsigned)a | ((unsigned)(b & 2047) << 17);
    }
}

// ---------------------------------------------------------------------------
// Pass 3: per-bin counting sort -> per-vertex CSR (adj, vstart, cnt). One
// block (1024 thr) per bin; reads its contiguous ~41K-entry run twice; the
// scattered adj writes are confined to the bin's ~163 KB window (L2-local).
// ---------------------------------------------------------------------------
__global__ __launch_bounds__(1024)
void sort2_kernel(const unsigned* __restrict__ rbuf, const int* __restrict__ binbase,
                  const int* __restrict__ bintot, unsigned* __restrict__ adj,
                  int* __restrict__ vstart, int* __restrict__ cnt) {
    __shared__ int h[2048];
    __shared__ int cur[2048];
    const int b = blockIdx.x;
    const int nE = bintot[b];
    const int rb = binbase[b];
    const int tid = threadIdx.x;
    const int i0 = tid, i1 = tid + 1024;
    h[i0] = 0; h[i1] = 0;
    __syncthreads();
    for (int i = tid; i < nE; i += 1024)
        atomicAdd(&h[rbuf[rb + i] >> 17], 1);
    __syncthreads();
    const int c0 = h[i0], c1 = h[i1];
    for (int off = 1; off < 2048; off <<= 1) {
        const int v0 = (i0 >= off) ? h[i0 - off] : 0;
        const int v1 = (i1 >= off) ? h[i1 - off] : 0;
        __syncthreads();
        h[i0] += v0; h[i1] += v1;
        __syncthreads();
    }
    cur[i0] = h[i0] - c0;                   // exclusive prefix within bin
    cur[i1] = h[i1] - c1;
    const int vb0 = b << BINSH;
    if (vb0 + i0 < NV) { vstart[vb0 + i0] = rb + h[i0] - c0; cnt[vb0 + i0] = c0; }
    if (vb0 + i1 < NV) { vstart[vb0 + i1] = rb + h[i1] - c1; cnt[vb0 + i1] = c1; }
    __syncthreads();
    for (int i = tid; i < nE; i += 1024) {
        const unsigned e = rbuf[rb + i];
        const int p = atomicAdd(&cur[e >> 17], 1);
        adj[rb + p] = e & 0x1FFFFu;
    }
}

// ---------------------------------------------------------------------------
// Gather (R12's proven gather3): one wave per vertex; 4 rows in flight,
// register accumulate, shfl-broadcast neighbor ids; any degree via 64-chunks.
// Output packed bf16 (sbf) — same rounding point matvec applied anyway.
// ---------------------------------------------------------------------------
__device__ __forceinline__ void acc4(float4& a, uint2 w) {
    a.x += __uint_as_float(w.x << 16);
    a.y += __uint_as_float(w.x & 0xffff0000u);
    a.z += __uint_as_float(w.y << 16);
    a.w += __uint_as_float(w.y & 0xffff0000u);
}

__global__ __launch_bounds__(256)
void gather8_kernel(const uint2* __restrict__ vbf, const unsigned* __restrict__ adj,
                    const int* __restrict__ vstart, const int* __restrict__ cnt,
                    unsigned* __restrict__ sbf) {
    const int lane = threadIdx.x & 63;
    const int sub = lane & 15;
    const int grp = lane >> 4;
    const int v = (int)((blockIdx.x * blockDim.x + threadIdx.x) >> 6);
    if (v >= NV) return;

    const int dg = cnt[v];
    const int base = vstart[v];

    float4 a0 = {0.f, 0.f, 0.f, 0.f}, a1 = a0, a2 = a0, a3 = a0;
    for (int done = 0; done < dg; done += 64) {
        const int rem = dg - done;
        const int m = rem < 64 ? rem : 64;
        const int myc = (lane < m) ? (int)adj[base + done + lane] : 0;
        int j = 0;
        for (; j + 16 <= m; j += 16) {
            const int ii = j + grp;
            const int c0 = __shfl(myc, ii, 64);
            const int c1 = __shfl(myc, ii + 4, 64);
            const int c2 = __shfl(myc, ii + 8, 64);
            const int c3 = __shfl(myc, ii + 12, 64);
            const uint2 w0 = vbf[(long)c0 * 16 + sub];
            const uint2 w1 = vbf[(long)c1 * 16 + sub];
            const uint2 w2 = vbf[(long)c2 * 16 + sub];
            const uint2 w3 = vbf[(long)c3 * 16 + sub];
            acc4(a0, w0); acc4(a1, w1); acc4(a2, w2); acc4(a3, w3);
        }
#pragma unroll
        for (int t = 0; t < 4; ++t) {
            const int ii = j + grp + 4 * t;
            const int c = __shfl(myc, ii < 63 ? ii : 63, 64);
            if (ii < m) acc4(a0, vbf[(long)c * 16 + sub]);
        }
    }

    a0.x += (a1.x + a2.x) + a3.x;
    a0.y += (a1.y + a2.y) + a3.y;
    a0.z += (a1.z + a2.z) + a3.z;
    a0.w += (a1.w + a2.w) + a3.w;
    a0.x += __shfl_xor(a0.x, 16, 64); a0.y += __shfl_xor(a0.y, 16, 64);
    a0.z += __shfl_xor(a0.z, 16, 64); a0.w += __shfl_xor(a0.w, 16, 64);
    a0.x += __shfl_xor(a0.x, 32, 64); a0.y += __shfl_xor(a0.y, 32, 64);
    a0.z += __shfl_xor(a0.z, 32, 64); a0.w += __shfl_xor(a0.w, 32, 64);

    if (lane < 16) {
        uint2 o;
        o.x = f2bf1(a0.x) | (f2bf1(a0.y) << 16);
        o.y = f2bf1(a0.z) | (f2bf1(a0.w) << 16);
        ((uint2*)sbf)[(size_t)v * 16 + sub] = o;
    }
}

// ---------------------------------------------------------------------------
// MFMA matvec: out[V,64] = A(V x 128) @ Bw(128 x 64) + b0 + deg*b1, where
// A = [x_bf16 | s_bf16], Bw = [W0^T; W1^T]. mfma_f32_16x16x32_bf16:
//   A-frag:  lane holds A[m = lane&15][k = quad*8 + j]
//   B-frag:  lane holds B[k = quad*8 + j][n = lane&15]  (mirror of A)
//   C/D:     lane holds D[row = quad*4 + reg][col = lane&15]
// One wave per 16-vertex tile; 16 B-frags hoisted (weights, L2-hot).
// A chunks 0,1 read vbf; chunks 2,3 read sbf (both bf16 rows, 128 B).
// ---------------------------------------------------------------------------
__global__ __launch_bounds__(256)
void matvec_mfma_kernel(const uint2* __restrict__ vbf,
                        const unsigned* __restrict__ sbf,
                        const float* __restrict__ w0,
                        const float* __restrict__ b0,
                        const float* __restrict__ w1,
                        const float* __restrict__ b1,
                        const int* __restrict__ cnt,
                        float* __restrict__ out) {
    const int lane = threadIdx.x & 63;
    const int quad = lane >> 4;
    const int n = lane & 15;
    const int wave = (int)((blockIdx.x * blockDim.x + threadIdx.x) >> 6);
    const int nwaves = (int)((gridDim.x * blockDim.x) >> 6);

    // Hoist 16 B-fragments: B[c][t], c = K-chunk (0,1: W0; 2,3: W1), t = col-tile.
    // B[k_g][n_g] = W[d = t*16+n][k = (c&1)*32 + quad*8 + j]  (y_d = sum_k W[d][k] A[k])
    short8 B[4][4];
#pragma unroll
    for (int c = 0; c < 4; ++c) {
        const float* wsrc = (c < 2) ? w0 : w1;
        const int kb = (c & 1) * 32 + quad * 8;
#pragma unroll
        for (int t = 0; t < 4; ++t) {
            const int d = t * 16 + n;
            const float4 p = *(const float4*)(wsrc + d * DIM + kb);
            const float4 q = *(const float4*)(wsrc + d * DIM + kb + 4);
            B[c][t] = pack_bf8(p, q);
        }
    }
    float bias0[4], bias1[4];
#pragma unroll
    for (int t = 0; t < 4; ++t) { bias0[t] = b0[t * 16 + n]; bias1[t] = b1[t * 16 + n]; }

    const short8* vb8 = (const short8*)vbf;    // 8 uint16 = 16 B per frag
    const short8* sb8 = (const short8*)sbf;

    for (int tile = wave; tile < NTILE; tile += nwaves) {
        const int base = tile * 16;
        const long v = base + n;               // this lane's A row
        f32x4 acc[4] = {{0.f,0.f,0.f,0.f},{0.f,0.f,0.f,0.f},
                        {0.f,0.f,0.f,0.f},{0.f,0.f,0.f,0.f}};

        // K-chunks 0,1: x rows from vbf
#pragma unroll
        for (int c = 0; c < 2; ++c) {
            const short8 A = vb8[v * 8 + c * 4 + quad];
#pragma unroll
            for (int t = 0; t < 4; ++t)
                acc[t] = __builtin_amdgcn_mfma_f32_16x16x32_bf16(A, B[c][t], acc[t], 0, 0, 0);
        }
        // K-chunks 2,3: s rows from sbf (already bf16)
#pragma unroll
        for (int c = 2; c < 4; ++c) {
            const short8 A = sb8[v * 8 + (c - 2) * 4 + quad];
#pragma unroll
            for (int t = 0; t < 4; ++t)
                acc[t] = __builtin_amdgcn_mfma_f32_16x16x32_bf16(A, B[c][t], acc[t], 0, 0, 0);
        }
        // Epilogue: D[row=quad*4+reg][col=n] + b0[d] + deg*b1[d]
#pragma unroll
        for (int r = 0; r < 4; ++r) {
            const int row = base + quad * 4 + r;
            const float dg = (float)cnt[row];
#pragma unroll
            for (int t = 0; t < 4; ++t)
                out[(long)row * DIM + t * 16 + n] = acc[t][r] + fmaf(dg, bias1[t], bias0[t]);
        }
    }
}

// ==========================================================================

extern "C" void kernel_launch(void* const* d_in, const int* in_sizes, int n_in,
                              void* d_out, int out_size, void* d_ws, size_t ws_size,
                              hipStream_t stream) {
    const float* verts = (const float*)d_in[0];
    const int*   edges = (const int*)d_in[1];
    const float* w0_w  = (const float*)d_in[2];
    const float* w0_b  = (const float*)d_in[3];
    const float* w1_w  = (const float*)d_in[4];
    const float* w1_b  = (const float*)d_in[5];
    float* out = (float*)d_out;

    // Workspace: vbf | sbf | rbuf | adj | cbnt | vstart | cnt | bintot |
    // binbase. Everything fully written -> no memset.
    char* p = (char*)d_ws;
    uint2*    vbf     = (uint2*)p;    p += (size_t)NV * DIM * 2;
    unsigned* sbf     = (unsigned*)p; p += (size_t)NV * DIM * 2;
    unsigned* rbuf    = (unsigned*)p; p += (size_t)2 * NE * 4;
    unsigned* adj     = (unsigned*)p; p += (size_t)2 * NE * 4;
    int*      cbnt    = (int*)p;      p += (size_t)NBIN * NBLK * 4;
    int*      vstart  = (int*)p;      p += (size_t)NV * 4;
    int*      cnt     = (int*)p;      p += (size_t)NV * 4;
    int*      bintot  = (int*)p;      p += ((size_t)NBIN * 4 + 15) & ~(size_t)15;
    int*      binbase = (int*)p;      p += ((size_t)NBIN * 4 + 15) & ~(size_t)15;

    hist_kernel<<<NBLK, NTHR, 0, stream>>>(edges, cbnt, verts, vbf);
    scanb_kernel<<<NBIN, 256, 0, stream>>>(cbnt, bintot);
    scanc_kernel<<<1, 64, 0, stream>>>(bintot, binbase);
    route_kernel<<<NBLK, NTHR, 0, stream>>>(edges, cbnt, binbase, rbuf);
    sort2_kernel<<<NBIN, 1024, 0, stream>>>(rbuf, binbase, bintot, adj, vstart, cnt);
    gather8_kernel<<<NV / 4, 256, 0, stream>>>(vbf, adj, vstart, cnt, sbf);
    // 6250 tiles, one per wave: 1563 blocks x 4 waves (grid-stride guard)
    matvec_mfma_kernel<<<1563, 256, 0, stream>>>(vbf, sbf, w0_w, w0_b,
                                                 w1_w, w1_b, cnt, out);
}

// Round 6
// 197.784 us; speedup vs baseline: 5.0015x; 1.1136x over previous
//
#include <hip/hip_runtime.h>
#include <hip/hip_bf16.h>

// GraphConv: out = verts@W0^T + b0 + scatter_sum_undirected(verts@W1^T + b1)
// V=100000, E=1000000, D=64. fp32 in/out; edges int64 (or int32) detected.
//
// R15 -> R16: gather back at its proven 47.5us, but "rest" has been ~165-173us
// across THREE different routing structures => the cost is the machinery
// (7 launches, 2 HBM edge passes, 2 scan kernels, 49-block sort) not any one
// pass. Collapse:
//   route1: ONE kernel (256x1024) = count chunk in LDS (196 bins x 512 verts)
//           -> reserve runs via ONE padded global atomicAdd per (block,bin)
//           (50K atomics on line-padded cursors) -> place chunk (L2-hot
//           re-read, same kernel). prep fused. No scans, no cntmat.
//   sort2:  196 blocks (was 49): per-bin counting sort -> per-vertex CSR in
//           the bin's 40KB window (L2-local). 77% CU fill.
//   gather9: proven wave-per-vertex register gather, rows as dwordx4 with
//           8 lanes/row (8 rows/instruction): half the loads+bpermutes of
//           gather8 at the same segment count; shfl_xor(8/16/32) epilogue.
//   matvec: MFMA [X|S] @ [W0;W1]^T (unchanged).
// Run order within bins is nondeterministic (atomic reservation) — harmless
// for a commutative sum within bf16 tolerance.

#define NV 100000
#define NE 1000000
#define DIM 64
#define BINSH 9                            // 512 vertices per bin
#define BINSZ 512
#define NBIN ((NV + BINSZ - 1) / BINSZ)    // 196
#define CAPB 16384                         // slots per bin (mean 10.2K, +60 sigma)
#define NBLK 256                           // route1 blocks
#define NTHR 1024                          // route1/sort2 threads per block
#define EPB ((NE + NBLK - 1) / NBLK)       // 3907 edges per block
#define NTILE (NV / 16)                    // 6250 MFMA row-tiles exactly

typedef __attribute__((ext_vector_type(8))) short short8;   // 8 bf16
typedef __attribute__((ext_vector_type(4))) float f32x4;

// Per-wave edge-layout detection. int64 words: [a_lo,a_hi,...], hi==0 always
// (idx < 100000). int32 words: odd words random in [0,V). First 64 odd words
// all zero => int64 (FP prob ~ V^-64 ~ 0). Reads are L2-hot after first wave.
__device__ __forceinline__ bool detect_is64(const int* __restrict__ edges) {
    int v = edges[2 * (threadIdx.x & 63) + 1];
    return __ballot(v != 0) == 0ull;
}

__device__ __forceinline__ unsigned f2bf1(float f) {  // RNE fp32 -> bf16 bits
    unsigned u = __float_as_uint(f);
    return (u + 0x7fffu + ((u >> 16) & 1u)) >> 16;
}

__device__ __forceinline__ float bflo(unsigned u) { return __uint_as_float(u << 16); }
__device__ __forceinline__ float bfhi(unsigned u) { return __uint_as_float(u & 0xffff0000u); }

__device__ __forceinline__ short8 pack_bf8(float4 a, float4 b) {
    short8 r;
    r[0] = (short)f2bf1(a.x); r[1] = (short)f2bf1(a.y);
    r[2] = (short)f2bf1(a.z); r[3] = (short)f2bf1(a.w);
    r[4] = (short)f2bf1(b.x); r[5] = (short)f2bf1(b.y);
    r[6] = (short)f2bf1(b.z); r[7] = (short)f2bf1(b.w);
    return r;
}

// ---------------------------------------------------------------------------
// route1: count -> reserve -> place, one kernel. gcur is line-padded
// (32 ints per bin) so the 256 same-bin atomics hit a private 128B line.
// Entry: n (17b) | vlocal (9b) << 17. Fused prep: verts fp32 -> vbf bf16.
// ---------------------------------------------------------------------------
__global__ __launch_bounds__(NTHR)
void route1_kernel(const int* __restrict__ edges, const float* __restrict__ verts,
                   uint2* __restrict__ vbf, int* __restrict__ gcur,
                   unsigned* __restrict__ rbuf) {
    __shared__ int cnt[NBIN];
    __shared__ int pos[NBIN];
    __shared__ int lcur[NBIN];
    const int tid = threadIdx.x;
    if (tid < NBIN) { cnt[tid] = 0; lcur[tid] = 0; }
    const bool is64 = detect_is64(edges);
    __syncthreads();

    const int eb = blockIdx.x * EPB;
    const int ee = min(NE, eb + EPB);
    // Pass A: count this block's chunk into 196 LDS bins.
    for (int e = eb + tid; e < ee; e += NTHR) {
        int a, b;
        if (is64) { int4 q = ((const int4*)edges)[e]; a = q.x; b = q.z; }
        else      { int2 q = ((const int2*)edges)[e]; a = q.x; b = q.y; }
        atomicAdd(&cnt[a >> BINSH], 1);
        atomicAdd(&cnt[b >> BINSH], 1);
    }
    __syncthreads();
    // Reserve: one global returning atomic per (block,bin).
    if (tid < NBIN) pos[tid] = (cnt[tid] > 0) ? atomicAdd(&gcur[tid * 32], cnt[tid]) : 0;
    __syncthreads();
    // Pass B: place (chunk re-read is L1/L2-hot).
    for (int e = eb + tid; e < ee; e += NTHR) {
        int a, b;
        if (is64) { int4 q = ((const int4*)edges)[e]; a = q.x; b = q.z; }
        else      { int2 q = ((const int2*)edges)[e]; a = q.x; b = q.y; }
        const int ka = a >> BINSH;
        const int sa = pos[ka] + atomicAdd(&lcur[ka], 1);
        if (sa < CAPB) rbuf[ka * CAPB + sa] = (unsigned)b | ((unsigned)(a & (BINSZ - 1)) << 17);
        const int kb = b >> BINSH;
        const int sb = pos[kb] + atomicAdd(&lcur[kb], 1);
        if (sb < CAPB) rbuf[kb * CAPB + sb] = (unsigned)a | ((unsigned)(b & (BINSZ - 1)) << 17);
    }

    // Fused prep: one float4 per iter -> uint2 (4 bf16). Independent of above.
    const long np = (long)NV * (DIM / 4);
    for (long i = (long)blockIdx.x * NTHR + tid; i < np; i += (long)NTHR * NBLK) {
        float4 v = ((const float4*)verts)[i];
        uint2 w;
        w.x = f2bf1(v.x) | (f2bf1(v.y) << 16);
        w.y = f2bf1(v.z) | (f2bf1(v.w) << 16);
        vbf[i] = w;
    }
}

// ---------------------------------------------------------------------------
// sort2: one block (1024 thr) per bin. Counting-sort the bin's ~10K entries
// to per-vertex CSR (adj, vstart, cnt). Scattered writes stay in the bin's
// 40KB window (L2-local).
// ---------------------------------------------------------------------------
__global__ __launch_bounds__(NTHR)
void sort2_kernel(const unsigned* __restrict__ rbuf, const int* __restrict__ gcur,
                  unsigned* __restrict__ adj, int* __restrict__ vstart,
                  int* __restrict__ cnt) {
    __shared__ int h[BINSZ];
    __shared__ int s[BINSZ];
    __shared__ int cur[BINSZ];
    const int b = blockIdx.x;
    const int rb = b * CAPB;
    const int tid = threadIdx.x;
    int nE = gcur[b * 32]; if (nE > CAPB) nE = CAPB;
    if (tid < BINSZ) h[tid] = 0;
    __syncthreads();
    for (int i = tid; i < nE; i += NTHR)
        atomicAdd(&h[rbuf[rb + i] >> 17], 1);
    __syncthreads();
    if (tid < BINSZ) s[tid] = h[tid];
    __syncthreads();
    for (int off = 1; off < BINSZ; off <<= 1) {
        const int v = (tid < BINSZ && tid >= off) ? s[tid - off] : 0;
        __syncthreads();
        if (tid < BINSZ) s[tid] += v;
        __syncthreads();
    }
    if (tid < BINSZ) {
        const int ex = s[tid] - h[tid];     // exclusive prefix within bin
        cur[tid] = ex;
        const int v = (b << BINSH) + tid;
        if (v < NV) { vstart[v] = rb + ex; cnt[v] = h[tid]; }
    }
    __syncthreads();
    for (int i = tid; i < nE; i += NTHR) {
        const unsigned e = rbuf[rb + i];
        const int p = atomicAdd(&cur[e >> 17], 1);
        adj[rb + p] = e & 0x1FFFFu;
    }
}

// ---------------------------------------------------------------------------
// gather9: wave per vertex; 8 rows per dwordx4 instruction (8 lanes/row,
// lane&7 = 16B chunk = 8 features). Register accumulate (8 fp32/lane),
// shfl-broadcast ids, 3-round shfl_xor(8/16/32) epilogue reduce; lanes 0..7
// write the packed 128B bf16 row.
// ---------------------------------------------------------------------------
__global__ __launch_bounds__(256)
void gather9_kernel(const uint2* __restrict__ vbf, const unsigned* __restrict__ adj,
                    const int* __restrict__ vstart, const int* __restrict__ cnt,
                    unsigned* __restrict__ sbf) {
    const int lane = threadIdx.x & 63;
    const int grp = lane >> 3;              // neighbor slot 0..7
    const int sub = lane & 7;               // 16B chunk within the 128B row
    const int v = (int)((blockIdx.x * blockDim.x + threadIdx.x) >> 6);

    const int dg = cnt[v];
    const int base = vstart[v];
    const uint4* __restrict__ vrow = (const uint4*)vbf;    // 8 uint4 per row

    float a0 = 0.f, a1 = 0.f, a2 = 0.f, a3 = 0.f;
    float a4 = 0.f, a5 = 0.f, a6 = 0.f, a7 = 0.f;
    for (int done = 0; done < dg; done += 64) {
        const int rem = dg - done;
        const int m = rem < 64 ? rem : 64;
        const int myc = (lane < m) ? (int)adj[base + done + lane] : 0;
        for (int j = 0; j < m; j += 8) {
            const int ii = j + grp;
            const int c = __shfl(myc, ii, 64);
            if (ii < m) {
                const uint4 w = vrow[(size_t)c * 8 + sub];
                a0 += bflo(w.x); a1 += bfhi(w.x);
                a2 += bflo(w.y); a3 += bfhi(w.y);
                a4 += bflo(w.z); a5 += bfhi(w.z);
                a6 += bflo(w.w); a7 += bfhi(w.w);
            }
        }
    }
    // Reduce across the 8 neighbor-slot groups (same sub, different grp).
#pragma unroll
    for (int off = 8; off < 64; off <<= 1) {
        a0 += __shfl_xor(a0, off, 64); a1 += __shfl_xor(a1, off, 64);
        a2 += __shfl_xor(a2, off, 64); a3 += __shfl_xor(a3, off, 64);
        a4 += __shfl_xor(a4, off, 64); a5 += __shfl_xor(a5, off, 64);
        a6 += __shfl_xor(a6, off, 64); a7 += __shfl_xor(a7, off, 64);
    }
    if (lane < 8) {
        uint4 o;
        o.x = f2bf1(a0) | (f2bf1(a1) << 16);
        o.y = f2bf1(a2) | (f2bf1(a3) << 16);
        o.z = f2bf1(a4) | (f2bf1(a5) << 16);
        o.w = f2bf1(a6) | (f2bf1(a7) << 16);
        ((uint4*)sbf)[(size_t)v * 8 + sub] = o;
    }
}

// ---------------------------------------------------------------------------
// MFMA matvec: out[V,64] = A(V x 128) @ Bw(128 x 64) + b0 + deg*b1, where
// A = [x_bf16 | s_bf16], Bw = [W0^T; W1^T]. mfma_f32_16x16x32_bf16:
//   A-frag:  lane holds A[m = lane&15][k = quad*8 + j]
//   B-frag:  lane holds B[k = quad*8 + j][n = lane&15]  (mirror of A)
//   C/D:     lane holds D[row = quad*4 + reg][col = lane&15]
// One wave per 16-vertex tile; 16 B-frags hoisted (weights, L2-hot).
// A chunks 0,1 read vbf; chunks 2,3 read sbf (both bf16 rows, 128 B).
// ---------------------------------------------------------------------------
__global__ __launch_bounds__(256)
void matvec_mfma_kernel(const uint2* __restrict__ vbf,
                        const unsigned* __restrict__ sbf,
                        const float* __restrict__ w0,
                        const float* __restrict__ b0,
                        const float* __restrict__ w1,
                        const float* __restrict__ b1,
                        const int* __restrict__ cnt,
                        float* __restrict__ out) {
    const int lane = threadIdx.x & 63;
    const int quad = lane >> 4;
    const int n = lane & 15;
    const int wave = (int)((blockIdx.x * blockDim.x + threadIdx.x) >> 6);
    const int nwaves = (int)((gridDim.x * blockDim.x) >> 6);

    // Hoist 16 B-fragments: B[c][t], c = K-chunk (0,1: W0; 2,3: W1), t = col-tile.
    // B[k_g][n_g] = W[d = t*16+n][k = (c&1)*32 + quad*8 + j]  (y_d = sum_k W[d][k] A[k])
    short8 B[4][4];
#pragma unroll
    for (int c = 0; c < 4; ++c) {
        const float* wsrc = (c < 2) ? w0 : w1;
        const int kb = (c & 1) * 32 + quad * 8;
#pragma unroll
        for (int t = 0; t < 4; ++t) {
            const int d = t * 16 + n;
            const float4 p = *(const float4*)(wsrc + d * DIM + kb);
            const float4 q = *(const float4*)(wsrc + d * DIM + kb + 4);
            B[c][t] = pack_bf8(p, q);
        }
    }
    float bias0[4], bias1[4];
#pragma unroll
    for (int t = 0; t < 4; ++t) { bias0[t] = b0[t * 16 + n]; bias1[t] = b1[t * 16 + n]; }

    const short8* vb8 = (const short8*)vbf;    // 8 uint16 = 16 B per frag
    const short8* sb8 = (const short8*)sbf;

    for (int tile = wave; tile < NTILE; tile += nwaves) {
        const int base = tile * 16;
        const long v = base + n;               // this lane's A row
        f32x4 acc[4] = {{0.f,0.f,0.f,0.f},{0.f,0.f,0.f,0.f},
                        {0.f,0.f,0.f,0.f},{0.f,0.f,0.f,0.f}};

        // K-chunks 0,1: x rows from vbf
#pragma unroll
        for (int c = 0; c < 2; ++c) {
            const short8 A = vb8[v * 8 + c * 4 + quad];
#pragma unroll
            for (int t = 0; t < 4; ++t)
                acc[t] = __builtin_amdgcn_mfma_f32_16x16x32_bf16(A, B[c][t], acc[t], 0, 0, 0);
        }
        // K-chunks 2,3: s rows from sbf (already bf16)
#pragma unroll
        for (int c = 2; c < 4; ++c) {
            const short8 A = sb8[v * 8 + (c - 2) * 4 + quad];
#pragma unroll
            for (int t = 0; t < 4; ++t)
                acc[t] = __builtin_amdgcn_mfma_f32_16x16x32_bf16(A, B[c][t], acc[t], 0, 0, 0);
        }
        // Epilogue: D[row=quad*4+reg][col=n] + b0[d] + deg*b1[d]
#pragma unroll
        for (int r = 0; r < 4; ++r) {
            const int row = base + quad * 4 + r;
            const float dg = (float)cnt[row];
#pragma unroll
            for (int t = 0; t < 4; ++t)
                out[(long)row * DIM + t * 16 + n] = acc[t][r] + fmaf(dg, bias1[t], bias0[t]);
        }
    }
}

// ==========================================================================

extern "C" void kernel_launch(void* const* d_in, const int* in_sizes, int n_in,
                              void* d_out, int out_size, void* d_ws, size_t ws_size,
                              hipStream_t stream) {
    const float* verts = (const float*)d_in[0];
    const int*   edges = (const int*)d_in[1];
    const float* w0_w  = (const float*)d_in[2];
    const float* w0_b  = (const float*)d_in[3];
    const float* w1_w  = (const float*)d_in[4];
    const float* w1_b  = (const float*)d_in[5];
    float* out = (float*)d_out;

    // Workspace: vbf | sbf | rbuf | adj | vstart | cnt | gcur (line-padded).
    char* p = (char*)d_ws;
    uint2*    vbf     = (uint2*)p;    p += (size_t)NV * DIM * 2;
    unsigned* sbf     = (unsigned*)p; p += (size_t)NV * DIM * 2;
    unsigned* rbuf    = (unsigned*)p; p += (size_t)NBIN * CAPB * 4;
    unsigned* adj     = (unsigned*)p; p += (size_t)NBIN * CAPB * 4;
    int*      vstart  = (int*)p;      p += (size_t)NV * 4;
    int*      cnt     = (int*)p;      p += (size_t)NV * 4;
    int*      gcur    = (int*)p;      p += (size_t)NBIN * 32 * 4;

    hipMemsetAsync(gcur, 0, (size_t)NBIN * 32 * 4, stream);
    route1_kernel<<<NBLK, NTHR, 0, stream>>>(edges, verts, vbf, gcur, rbuf);
    sort2_kernel<<<NBIN, NTHR, 0, stream>>>(rbuf, gcur, adj, vstart, cnt);
    gather9_kernel<<<NV / 4, 256, 0, stream>>>(vbf, adj, vstart, cnt, sbf);
    // 6250 tiles, one per wave: 1563 blocks x 4 waves (grid-stride guard)
    matvec_mfma_kernel<<<1563, 256, 0, stream>>>(vbf, sbf, w0_w, w0_b,
                                                 w1_w, w1_b, cnt, out);
}

// Round 7
// 196.128 us; speedup vs baseline: 5.0438x; 1.0084x over previous
//
#include <hip/hip_runtime.h>
#include <hip/hip_bf16.h>

// GraphConv: out = verts@W0^T + b0 + scatter_sum_undirected(verts@W1^T + b1)
// V=100000, E=1000000, D=64. fp32 in/out; edges int64 (or int32) detected.
//
// R16 -> R17 (attribution round): rest-cost ~145-170us is invariant to launch
// count (7 vs 5) and routing structure => it's real kernel time in
// route1/sort2/matvec hidden below gather in the top-5 (which shows only the
// hottest kernel's iterations). This round:
//   1) gather split into TWO half-range launches (~24us each, same total) so
//      the hottest middle kernel surfaces in top-5.
//   2) gather10: 4-deep MLP inside the dwordx4 form — all four 8-row groups'
//      shfls+loads issued back-to-back (clamped idx, predicated adds); was 1
//      load in flight (shfl->load chain), now 4. Clamped dups are L1-hits.
//   FETCH insight: gather's 100MB = 8 XCDs x 12.8MB vbf — every XCD pulls the
//   whole vertex table once (random topology). Structural fabric floor.
//   route1/sort2/matvec unchanged from R16.

#define NV 100000
#define NE 1000000
#define DIM 64
#define BINSH 9                            // 512 vertices per bin
#define BINSZ 512
#define NBIN ((NV + BINSZ - 1) / BINSZ)    // 196
#define CAPB 16384                         // slots per bin (mean 10.2K, +60 sigma)
#define NBLK 256                           // route1 blocks
#define NTHR 1024                          // route1/sort2 threads per block
#define EPB ((NE + NBLK - 1) / NBLK)       // 3907 edges per block
#define NTILE (NV / 16)                    // 6250 MFMA row-tiles exactly

typedef __attribute__((ext_vector_type(8))) short short8;   // 8 bf16
typedef __attribute__((ext_vector_type(4))) float f32x4;

// Per-wave edge-layout detection. int64 words: [a_lo,a_hi,...], hi==0 always
// (idx < 100000). int32 words: odd words random in [0,V). First 64 odd words
// all zero => int64 (FP prob ~ V^-64 ~ 0). Reads are L2-hot after first wave.
__device__ __forceinline__ bool detect_is64(const int* __restrict__ edges) {
    int v = edges[2 * (threadIdx.x & 63) + 1];
    return __ballot(v != 0) == 0ull;
}

__device__ __forceinline__ unsigned f2bf1(float f) {  // RNE fp32 -> bf16 bits
    unsigned u = __float_as_uint(f);
    return (u + 0x7fffu + ((u >> 16) & 1u)) >> 16;
}

__device__ __forceinline__ float bflo(unsigned u) { return __uint_as_float(u << 16); }
__device__ __forceinline__ float bfhi(unsigned u) { return __uint_as_float(u & 0xffff0000u); }

__device__ __forceinline__ short8 pack_bf8(float4 a, float4 b) {
    short8 r;
    r[0] = (short)f2bf1(a.x); r[1] = (short)f2bf1(a.y);
    r[2] = (short)f2bf1(a.z); r[3] = (short)f2bf1(a.w);
    r[4] = (short)f2bf1(b.x); r[5] = (short)f2bf1(b.y);
    r[6] = (short)f2bf1(b.z); r[7] = (short)f2bf1(b.w);
    return r;
}

// ---------------------------------------------------------------------------
// route1: count -> reserve -> place, one kernel. gcur is line-padded
// (32 ints per bin) so the 256 same-bin atomics hit a private 128B line.
// Entry: n (17b) | vlocal (9b) << 17. Fused prep: verts fp32 -> vbf bf16.
// ---------------------------------------------------------------------------
__global__ __launch_bounds__(NTHR)
void route1_kernel(const int* __restrict__ edges, const float* __restrict__ verts,
                   uint2* __restrict__ vbf, int* __restrict__ gcur,
                   unsigned* __restrict__ rbuf) {
    __shared__ int cnt[NBIN];
    __shared__ int pos[NBIN];
    __shared__ int lcur[NBIN];
    const int tid = threadIdx.x;
    if (tid < NBIN) { cnt[tid] = 0; lcur[tid] = 0; }
    const bool is64 = detect_is64(edges);
    __syncthreads();

    const int eb = blockIdx.x * EPB;
    const int ee = min(NE, eb + EPB);
    // Pass A: count this block's chunk into 196 LDS bins.
    for (int e = eb + tid; e < ee; e += NTHR) {
        int a, b;
        if (is64) { int4 q = ((const int4*)edges)[e]; a = q.x; b = q.z; }
        else      { int2 q = ((const int2*)edges)[e]; a = q.x; b = q.y; }
        atomicAdd(&cnt[a >> BINSH], 1);
        atomicAdd(&cnt[b >> BINSH], 1);
    }
    __syncthreads();
    // Reserve: one global returning atomic per (block,bin).
    if (tid < NBIN) pos[tid] = (cnt[tid] > 0) ? atomicAdd(&gcur[tid * 32], cnt[tid]) : 0;
    __syncthreads();
    // Pass B: place (chunk re-read is L1/L2-hot).
    for (int e = eb + tid; e < ee; e += NTHR) {
        int a, b;
        if (is64) { int4 q = ((const int4*)edges)[e]; a = q.x; b = q.z; }
        else      { int2 q = ((const int2*)edges)[e]; a = q.x; b = q.y; }
        const int ka = a >> BINSH;
        const int sa = pos[ka] + atomicAdd(&lcur[ka], 1);
        if (sa < CAPB) rbuf[ka * CAPB + sa] = (unsigned)b | ((unsigned)(a & (BINSZ - 1)) << 17);
        const int kb = b >> BINSH;
        const int sb = pos[kb] + atomicAdd(&lcur[kb], 1);
        if (sb < CAPB) rbuf[kb * CAPB + sb] = (unsigned)a | ((unsigned)(b & (BINSZ - 1)) << 17);
    }

    // Fused prep: one float4 per iter -> uint2 (4 bf16). Independent of above.
    const long np = (long)NV * (DIM / 4);
    for (long i = (long)blockIdx.x * NTHR + tid; i < np; i += (long)NTHR * NBLK) {
        float4 v = ((const float4*)verts)[i];
        uint2 w;
        w.x = f2bf1(v.x) | (f2bf1(v.y) << 16);
        w.y = f2bf1(v.z) | (f2bf1(v.w) << 16);
        vbf[i] = w;
    }
}

// ---------------------------------------------------------------------------
// sort2: one block (1024 thr) per bin. Counting-sort the bin's ~10K entries
// to per-vertex CSR (adj, vstart, cnt). Scattered writes stay in the bin's
// 40KB window (L2-local).
// ---------------------------------------------------------------------------
__global__ __launch_bounds__(NTHR)
void sort2_kernel(const unsigned* __restrict__ rbuf, const int* __restrict__ gcur,
                  unsigned* __restrict__ adj, int* __restrict__ vstart,
                  int* __restrict__ cnt) {
    __shared__ int h[BINSZ];
    __shared__ int s[BINSZ];
    __shared__ int cur[BINSZ];
    const int b = blockIdx.x;
    const int rb = b * CAPB;
    const int tid = threadIdx.x;
    int nE = gcur[b * 32]; if (nE > CAPB) nE = CAPB;
    if (tid < BINSZ) h[tid] = 0;
    __syncthreads();
    for (int i = tid; i < nE; i += NTHR)
        atomicAdd(&h[rbuf[rb + i] >> 17], 1);
    __syncthreads();
    if (tid < BINSZ) s[tid] = h[tid];
    __syncthreads();
    for (int off = 1; off < BINSZ; off <<= 1) {
        const int v = (tid < BINSZ && tid >= off) ? s[tid - off] : 0;
        __syncthreads();
        if (tid < BINSZ) s[tid] += v;
        __syncthreads();
    }
    if (tid < BINSZ) {
        const int ex = s[tid] - h[tid];     // exclusive prefix within bin
        cur[tid] = ex;
        const int v = (b << BINSH) + tid;
        if (v < NV) { vstart[v] = rb + ex; cnt[v] = h[tid]; }
    }
    __syncthreads();
    for (int i = tid; i < nE; i += NTHR) {
        const unsigned e = rbuf[rb + i];
        const int p = atomicAdd(&cur[e >> 17], 1);
        adj[rb + p] = e & 0x1FFFFu;
    }
}

// ---------------------------------------------------------------------------
// gather10: wave per vertex; 8 rows per dwordx4 instruction (8 lanes/row),
// 4-deep MLP: all four 8-row groups of a 32-window issued back-to-back
// (clamped shfl idx, predicated adds -> dup loads are L1-hit broadcasts).
// Register accumulate; shfl_xor(8/16/32) epilogue; lanes 0..7 write the row.
// vbase splits the vertex range across two launches (top-5 attribution).
// ---------------------------------------------------------------------------
__global__ __launch_bounds__(256)
void gather10_kernel(const uint2* __restrict__ vbf, const unsigned* __restrict__ adj,
                     const int* __restrict__ vstart, const int* __restrict__ cnt,
                     unsigned* __restrict__ sbf, int vbase) {
    const int lane = threadIdx.x & 63;
    const int grp = lane >> 3;              // neighbor slot 0..7
    const int sub = lane & 7;               // 16B chunk within the 128B row
    const int v = vbase + (int)((blockIdx.x * blockDim.x + threadIdx.x) >> 6);

    const int dg = cnt[v];
    const int base = vstart[v];
    const uint4* __restrict__ vrow = (const uint4*)vbf;    // 8 uint4 per row

    float a0 = 0.f, a1 = 0.f, a2 = 0.f, a3 = 0.f;
    float a4 = 0.f, a5 = 0.f, a6 = 0.f, a7 = 0.f;
    for (int done = 0; done < dg; done += 64) {
        const int rem = dg - done;
        const int m = rem < 64 ? rem : 64;
        const int myc = (lane < m) ? (int)adj[base + done + lane] : 0;
        for (int j = 0; j < m; j += 32) {
            const int i0 = j + grp, i1 = j + 8 + grp, i2 = j + 16 + grp, i3 = j + 24 + grp;
            const int c0 = __shfl(myc, i0 < m ? i0 : 0, 64);
            const int c1 = __shfl(myc, i1 < m ? i1 : 0, 64);
            const int c2 = __shfl(myc, i2 < m ? i2 : 0, 64);
            const int c3 = __shfl(myc, i3 < m ? i3 : 0, 64);
            const uint4 w0 = vrow[(size_t)c0 * 8 + sub];
            const uint4 w1 = vrow[(size_t)c1 * 8 + sub];
            const uint4 w2 = vrow[(size_t)c2 * 8 + sub];
            const uint4 w3 = vrow[(size_t)c3 * 8 + sub];
            if (i0 < m) {
                a0 += bflo(w0.x); a1 += bfhi(w0.x); a2 += bflo(w0.y); a3 += bfhi(w0.y);
                a4 += bflo(w0.z); a5 += bfhi(w0.z); a6 += bflo(w0.w); a7 += bfhi(w0.w);
            }
            if (i1 < m) {
                a0 += bflo(w1.x); a1 += bfhi(w1.x); a2 += bflo(w1.y); a3 += bfhi(w1.y);
                a4 += bflo(w1.z); a5 += bfhi(w1.z); a6 += bflo(w1.w); a7 += bfhi(w1.w);
            }
            if (i2 < m) {
                a0 += bflo(w2.x); a1 += bfhi(w2.x); a2 += bflo(w2.y); a3 += bfhi(w2.y);
                a4 += bflo(w2.z); a5 += bfhi(w2.z); a6 += bflo(w2.w); a7 += bfhi(w2.w);
            }
            if (i3 < m) {
                a0 += bflo(w3.x); a1 += bfhi(w3.x); a2 += bflo(w3.y); a3 += bfhi(w3.y);
                a4 += bflo(w3.z); a5 += bfhi(w3.z); a6 += bflo(w3.w); a7 += bfhi(w3.w);
            }
        }
    }
    // Reduce across the 8 neighbor-slot groups (same sub, different grp).
#pragma unroll
    for (int off = 8; off < 64; off <<= 1) {
        a0 += __shfl_xor(a0, off, 64); a1 += __shfl_xor(a1, off, 64);
        a2 += __shfl_xor(a2, off, 64); a3 += __shfl_xor(a3, off, 64);
        a4 += __shfl_xor(a4, off, 64); a5 += __shfl_xor(a5, off, 64);
        a6 += __shfl_xor(a6, off, 64); a7 += __shfl_xor(a7, off, 64);
    }
    if (lane < 8) {
        uint4 o;
        o.x = f2bf1(a0) | (f2bf1(a1) << 16);
        o.y = f2bf1(a2) | (f2bf1(a3) << 16);
        o.z = f2bf1(a4) | (f2bf1(a5) << 16);
        o.w = f2bf1(a6) | (f2bf1(a7) << 16);
        ((uint4*)sbf)[(size_t)v * 8 + sub] = o;
    }
}

// ---------------------------------------------------------------------------
// MFMA matvec: out[V,64] = A(V x 128) @ Bw(128 x 64) + b0 + deg*b1, where
// A = [x_bf16 | s_bf16], Bw = [W0^T; W1^T]. mfma_f32_16x16x32_bf16:
//   A-frag:  lane holds A[m = lane&15][k = quad*8 + j]
//   B-frag:  lane holds B[k = quad*8 + j][n = lane&15]  (mirror of A)
//   C/D:     lane holds D[row = quad*4 + reg][col = lane&15]
// One wave per 16-vertex tile; 16 B-frags hoisted (weights, L2-hot).
// A chunks 0,1 read vbf; chunks 2,3 read sbf (both bf16 rows, 128 B).
// ---------------------------------------------------------------------------
__global__ __launch_bounds__(256)
void matvec_mfma_kernel(const uint2* __restrict__ vbf,
                        const unsigned* __restrict__ sbf,
                        const float* __restrict__ w0,
                        const float* __restrict__ b0,
                        const float* __restrict__ w1,
                        const float* __restrict__ b1,
                        const int* __restrict__ cnt,
                        float* __restrict__ out) {
    const int lane = threadIdx.x & 63;
    const int quad = lane >> 4;
    const int n = lane & 15;
    const int wave = (int)((blockIdx.x * blockDim.x + threadIdx.x) >> 6);
    const int nwaves = (int)((gridDim.x * blockDim.x) >> 6);

    // Hoist 16 B-fragments: B[c][t], c = K-chunk (0,1: W0; 2,3: W1), t = col-tile.
    // B[k_g][n_g] = W[d = t*16+n][k = (c&1)*32 + quad*8 + j]  (y_d = sum_k W[d][k] A[k])
    short8 B[4][4];
#pragma unroll
    for (int c = 0; c < 4; ++c) {
        const float* wsrc = (c < 2) ? w0 : w1;
        const int kb = (c & 1) * 32 + quad * 8;
#pragma unroll
        for (int t = 0; t < 4; ++t) {
            const int d = t * 16 + n;
            const float4 p = *(const float4*)(wsrc + d * DIM + kb);
            const float4 q = *(const float4*)(wsrc + d * DIM + kb + 4);
            B[c][t] = pack_bf8(p, q);
        }
    }
    float bias0[4], bias1[4];
#pragma unroll
    for (int t = 0; t < 4; ++t) { bias0[t] = b0[t * 16 + n]; bias1[t] = b1[t * 16 + n]; }

    const short8* vb8 = (const short8*)vbf;    // 8 uint16 = 16 B per frag
    const short8* sb8 = (const short8*)sbf;

    for (int tile = wave; tile < NTILE; tile += nwaves) {
        const int base = tile * 16;
        const long v = base + n;               // this lane's A row
        f32x4 acc[4] = {{0.f,0.f,0.f,0.f},{0.f,0.f,0.f,0.f},
                        {0.f,0.f,0.f,0.f},{0.f,0.f,0.f,0.f}};

        // K-chunks 0,1: x rows from vbf
#pragma unroll
        for (int c = 0; c < 2; ++c) {
            const short8 A = vb8[v * 8 + c * 4 + quad];
#pragma unroll
            for (int t = 0; t < 4; ++t)
                acc[t] = __builtin_amdgcn_mfma_f32_16x16x32_bf16(A, B[c][t], acc[t], 0, 0, 0);
        }
        // K-chunks 2,3: s rows from sbf (already bf16)
#pragma unroll
        for (int c = 2; c < 4; ++c) {
            const short8 A = sb8[v * 8 + (c - 2) * 4 + quad];
#pragma unroll
            for (int t = 0; t < 4; ++t)
                acc[t] = __builtin_amdgcn_mfma_f32_16x16x32_bf16(A, B[c][t], acc[t], 0, 0, 0);
        }
        // Epilogue: D[row=quad*4+reg][col=n] + b0[d] + deg*b1[d]
#pragma unroll
        for (int r = 0; r < 4; ++r) {
            const int row = base + quad * 4 + r;
            const float dg = (float)cnt[row];
#pragma unroll
            for (int t = 0; t < 4; ++t)
                out[(long)row * DIM + t * 16 + n] = acc[t][r] + fmaf(dg, bias1[t], bias0[t]);
        }
    }
}

// ==========================================================================

extern "C" void kernel_launch(void* const* d_in, const int* in_sizes, int n_in,
                              void* d_out, int out_size, void* d_ws, size_t ws_size,
                              hipStream_t stream) {
    const float* verts = (const float*)d_in[0];
    const int*   edges = (const int*)d_in[1];
    const float* w0_w  = (const float*)d_in[2];
    const float* w0_b  = (const float*)d_in[3];
    const float* w1_w  = (const float*)d_in[4];
    const float* w1_b  = (const float*)d_in[5];
    float* out = (float*)d_out;

    // Workspace: vbf | sbf | rbuf | adj | vstart | cnt | gcur (line-padded).
    char* p = (char*)d_ws;
    uint2*    vbf     = (uint2*)p;    p += (size_t)NV * DIM * 2;
    unsigned* sbf     = (unsigned*)p; p += (size_t)NV * DIM * 2;
    unsigned* rbuf    = (unsigned*)p; p += (size_t)NBIN * CAPB * 4;
    unsigned* adj     = (unsigned*)p; p += (size_t)NBIN * CAPB * 4;
    int*      vstart  = (int*)p;      p += (size_t)NV * 4;
    int*      cnt     = (int*)p;      p += (size_t)NV * 4;
    int*      gcur    = (int*)p;      p += (size_t)NBIN * 32 * 4;

    hipMemsetAsync(gcur, 0, (size_t)NBIN * 32 * 4, stream);
    route1_kernel<<<NBLK, NTHR, 0, stream>>>(edges, verts, vbf, gcur, rbuf);
    sort2_kernel<<<NBIN, NTHR, 0, stream>>>(rbuf, gcur, adj, vstart, cnt);
    // Two half-range gathers: surfaces the hottest middle kernel in top-5.
    gather10_kernel<<<NV / 8, 256, 0, stream>>>(vbf, adj, vstart, cnt, sbf, 0);
    gather10_kernel<<<NV / 8, 256, 0, stream>>>(vbf, adj, vstart, cnt, sbf, NV / 2);
    // 6250 tiles, one per wave: 1563 blocks x 4 waves (grid-stride guard)
    matvec_mfma_kernel<<<1563, 256, 0, stream>>>(vbf, sbf, w0_w, w0_b,
                                                 w1_w, w1_b, cnt, out);
}